// Round 11
// baseline (382.946 us; speedup 1.0000x reference)
//
#include <hip/hip_runtime.h>
#include <math.h>

static inline int cdiv(int a, int b){ return (a + b - 1) / b; }

typedef __attribute__((ext_vector_type(8))) short short8_t;   // 8 bf16 (4 VGPRs)
typedef __attribute__((ext_vector_type(4))) float f32x4;      // MFMA acc
typedef __attribute__((ext_vector_type(2))) float f32x2;

static __device__ inline unsigned short f2bf(float f) {       // fp32 -> bf16 RTNE
    union { float f; unsigned u; } v; v.f = f;
    unsigned r = v.u + 0x7fff + ((v.u >> 16) & 1);
    return (unsigned short)(r >> 16);
}

// ---- fp8 e4m3fn (OCP) helpers ----
static __device__ inline unsigned char f2fp8(float f) {       // RTNE, saturating
    union { float f; unsigned u; } v; v.f = f;
    unsigned s = (v.u >> 24) & 0x80u;
    v.u &= 0x7fffffffu;
    v.f = fminf(v.f, 448.f);
    unsigned out;
    if (v.u >= (121u << 23)) {                 // |x| >= 2^-6 : normal
        unsigned u = v.u + 0x7FFFFu + ((v.u >> 20) & 1u);
        out = (((u >> 23) - 120u) << 3) | ((u >> 20) & 7u);
    } else {                                   // denormal: round(x * 2^9)
        out = (unsigned)(v.f * 512.f + 0.5f);
    }
    return (unsigned char)(out | s);
}

static __device__ inline float fp8_1(unsigned b) {            // scalar decode (fallback)
    unsigned s = (b & 0x80u) << 24;
    unsigned em = b & 0x7fu;
    union { unsigned u; float f; } n;
    n.u = (((em >> 3) + 120u) << 23) | ((em & 7u) << 20);
    float mag = (em >= 8u) ? n.f : (float)em * 0.001953125f;
    union { unsigned u; float f; } r; r.f = mag; r.u |= s;
    return r.f;
}

static __device__ __forceinline__ f32x2 fp8lo(unsigned v) {   // bytes 0,1
#if __has_builtin(__builtin_amdgcn_cvt_pk_f32_fp8)
    return __builtin_amdgcn_cvt_pk_f32_fp8((int)v, false);
#else
    f32x2 r; r[0] = fp8_1(v & 0xff); r[1] = fp8_1((v >> 8) & 0xff); return r;
#endif
}
static __device__ __forceinline__ f32x2 fp8hi(unsigned v) {   // bytes 2,3
#if __has_builtin(__builtin_amdgcn_cvt_pk_f32_fp8)
    return __builtin_amdgcn_cvt_pk_f32_fp8((int)v, true);
#else
    f32x2 r; r[0] = fp8_1((v >> 16) & 0xff); r[1] = fp8_1(v >> 24); return r;
#endif
}

// ---------------- graph build (CSR by dst, self-loops folded in) ----------------

// XCD-windowed count (blocks < fillBlocks) + weight transpose/cast (trailing blocks).
__global__ __launch_bounds__(256) void k_count_prep(const int* __restrict__ dst, int E,
        int* __restrict__ deg, int wsize, int fillBlocks,
        const float* __restrict__ W1, const float* __restrict__ W2,
        const float* __restrict__ Wg, unsigned short* __restrict__ W1t,
        unsigned short* __restrict__ W2t, unsigned short* __restrict__ Wgt) {
    if (blockIdx.x >= fillBlocks) {            // weight prep tail: 256 blocks
        int t = (blockIdx.x - fillBlocks) * 256 + threadIdx.x;
        if (t < 65536) { int k = t >> 8, c = t & 255; W1t[c * 256 + k] = f2bf(W1[t]); }
        if (t < 8192)  { int k = t >> 7, c = t & 127; W2t[c * 64 + k]  = f2bf(W2[t]); }
        if (t < 2048)  { int k = t >> 5, c = t & 31;  Wgt[c * 64 + k]  = f2bf(Wg[t]); }
        return;
    }
    int win   = blockIdx.x & 7;
    int chunk = blockIdx.x >> 3;
    int lo = win * wsize, hi = lo + wsize;
    int base = (chunk * 256 + threadIdx.x) * 4;
    if (base + 3 < E) {
        int4 d = *(const int4*)(dst + base);
        if (d.x >= lo && d.x < hi) atomicAdd(&deg[d.x], 1);
        if (d.y >= lo && d.y < hi) atomicAdd(&deg[d.y], 1);
        if (d.z >= lo && d.z < hi) atomicAdd(&deg[d.z], 1);
        if (d.w >= lo && d.w < hi) atomicAdd(&deg[d.w], 1);
    } else {
        for (int k = 0; k < 4; k++) {
            int e = base + k;
            if (e < E) { int d = dst[e]; if (d >= lo && d < hi) atomicAdd(&deg[d], 1); }
        }
    }
}

__global__ void k_scan_partial(const int* __restrict__ deg, int n, int* __restrict__ partial) {
    __shared__ int sd[256];
    int base = blockIdx.x * 1024;
    int sum = 0;
    for (int i = threadIdx.x; i < 1024; i += 256) {
        int idx = base + i;
        if (idx < n) sum += deg[idx] + 1;          // +1: self loop
    }
    sd[threadIdx.x] = sum;
    __syncthreads();
    for (int s = 128; s > 0; s >>= 1) {
        if (threadIdx.x < s) sd[threadIdx.x] += sd[threadIdx.x + s];
        __syncthreads();
    }
    if (threadIdx.x == 0) partial[blockIdx.x] = sd[0];
}

// scan with in-kernel lookback + fused: offs, cursor init, self slot, dinv.
__global__ void k_scan_final(const int* __restrict__ deg, int n,
                             const int* __restrict__ partial, int* __restrict__ offs,
                             int* __restrict__ cursor, int* __restrict__ csr,
                             float* __restrict__ dinv) {
    __shared__ int sd[256];
    int tid = threadIdx.x;
    int pre = 0;
    for (int i = tid; i < (int)blockIdx.x; i += 256) pre += partial[i];
    sd[tid] = pre;
    __syncthreads();
    for (int s = 128; s > 0; s >>= 1) {
        if (tid < s) sd[tid] += sd[tid + s];
        __syncthreads();
    }
    int base_pre = sd[0];
    __syncthreads();
    int base = blockIdx.x * 1024;
    int v[4]; int s0 = 0;
    #pragma unroll
    for (int j = 0; j < 4; j++) {
        int idx = base + tid*4 + j;
        v[j] = (idx < n) ? (deg[idx] + 1) : 0;
        s0 += v[j];
    }
    sd[tid] = s0;
    __syncthreads();
    for (int st = 1; st < 256; st <<= 1) {
        int t = (tid >= st) ? sd[tid - st] : 0;
        __syncthreads();
        sd[tid] += t;
        __syncthreads();
    }
    int ex = (tid > 0 ? sd[tid - 1] : 0) + base_pre;
    #pragma unroll
    for (int j = 0; j < 4; j++) {
        int idx = base + tid*4 + j;
        if (idx < n) {
            offs[idx]   = ex;
            cursor[idx] = ex;
            dinv[idx]   = rsqrtf((float)v[j]);
            csr[ex + v[j] - 1] = idx;          // self slot (fill never touches it)
        }
        ex += v[j];
    }
    if (blockIdx.x == gridDim.x - 1 && tid == 255) offs[n] = ex;   // == E + N
}

// XCD-pinned windowed fill; skips src load when quad has no match.
__global__ __launch_bounds__(256) void k_fill_csr_win(const int* __restrict__ src,
        const int* __restrict__ dst, int E,
        int* __restrict__ cursor, int* __restrict__ csr, int wsize) {
    int win   = blockIdx.x & 7;
    int chunk = blockIdx.x >> 3;
    int lo = win * wsize, hi = lo + wsize;
    int base = (chunk * 256 + threadIdx.x) * 4;
    if (base + 3 < E) {
        int4 d = *(const int4*)(dst + base);
        bool ix = d.x >= lo && d.x < hi, iy = d.y >= lo && d.y < hi;
        bool iz = d.z >= lo && d.z < hi, iw = d.w >= lo && d.w < hi;
        if (ix | iy | iz | iw) {
            int4 s = *(const int4*)(src + base);
            if (ix) { int p = atomicAdd(&cursor[d.x], 1); csr[p] = s.x; }
            if (iy) { int p = atomicAdd(&cursor[d.y], 1); csr[p] = s.y; }
            if (iz) { int p = atomicAdd(&cursor[d.z], 1); csr[p] = s.z; }
            if (iw) { int p = atomicAdd(&cursor[d.w], 1); csr[p] = s.w; }
        }
    } else {
        for (int k = 0; k < 4; k++) {
            int e = base + k;
            if (e < E) {
                int d = dst[e];
                if (d >= lo && d < hi) { int p = atomicAdd(&cursor[d], 1); csr[p] = src[e]; }
            }
        }
    }
}

// ---------------- GEMM1: fp8 hpre + fused att-dots, via bf16 MFMA ----------------
// BM=128, BN=256 (full width), BK=64 (2 barriers per 64-k stage -> 8 total),
// 512 thr / 8 waves, wave tile 32x128.
__global__ __launch_bounds__(512) void k_gemm1_mfma(const float* __restrict__ A,
        const unsigned short* __restrict__ Bt, const float* __restrict__ att_s_g,
        const float* __restrict__ att_d_g, unsigned char* __restrict__ C,
        float* __restrict__ out_as, float* __restrict__ out_ad, int M) {
    constexpr int LDP = 72;                    // 64 bf16 + 8 pad = 144 B row (2-way banks: free)
    __shared__ __align__(16) unsigned short As[128 * LDP];   // 18.4 KB
    __shared__ __align__(16) unsigned short Bs[256 * LDP];   // 36.9 KB
    __shared__ float att_l[512];               // [0:256) att_s, [256:512) att_d (flat col)
    int tid = threadIdx.x;
    int bm = blockIdx.x * 128;
    int wave = tid >> 6, lane = tid & 63;
    int wr = wave >> 1, wc = wave & 1;
    int lg = lane >> 4, lr = lane & 15;

    att_l[tid] = (tid < 256) ? att_s_g[tid] : att_d_g[tid - 256];

    f32x4 acc[2][8] = {};

    for (int k0 = 0; k0 < 256; k0 += 64) {
        __syncthreads();
        {   // stage A: 128 rows x 64 k fp32 -> bf16 (16 floats/thread)
            int row = tid >> 2, part = tid & 3;
            int gr = bm + row;
            float4 v0, v1, v2, v3;
            if (gr < M) {
                const float4* p = (const float4*)(A + (size_t)gr * 256 + k0 + part * 16);
                v0 = p[0]; v1 = p[1]; v2 = p[2]; v3 = p[3];
            } else {
                v0 = make_float4(0.f,0.f,0.f,0.f); v1 = v0; v2 = v0; v3 = v0;
            }
            unsigned short* w = &As[row * LDP + part * 16];
            w[0]=f2bf(v0.x);  w[1]=f2bf(v0.y);  w[2]=f2bf(v0.z);  w[3]=f2bf(v0.w);
            w[4]=f2bf(v1.x);  w[5]=f2bf(v1.y);  w[6]=f2bf(v1.z);  w[7]=f2bf(v1.w);
            w[8]=f2bf(v2.x);  w[9]=f2bf(v2.y);  w[10]=f2bf(v2.z); w[11]=f2bf(v2.w);
            w[12]=f2bf(v3.x); w[13]=f2bf(v3.y); w[14]=f2bf(v3.z); w[15]=f2bf(v3.w);
        }
        {   // stage B: 256 cols x 64 k bf16 copy (64 B/thread)
            int col = tid >> 1, part = tid & 1;
            const uint4* p = (const uint4*)(Bt + (size_t)col * 256 + k0 + part * 32);
            uint4 u0 = p[0], u1 = p[1], u2 = p[2], u3 = p[3];
            unsigned short* w = &Bs[col * LDP + part * 32];
            *(uint4*)(w)      = u0;
            *(uint4*)(w + 8)  = u1;
            *(uint4*)(w + 16) = u2;
            *(uint4*)(w + 24) = u3;
        }
        __syncthreads();
        #pragma unroll
        for (int kh = 0; kh < 2; kh++) {
            short8_t a[2], b[8];
            #pragma unroll
            for (int i = 0; i < 2; i++)
                a[i] = *(const short8_t*)&As[(wr * 32 + i * 16 + lr) * LDP + kh * 32 + lg * 8];
            #pragma unroll
            for (int j = 0; j < 8; j++)
                b[j] = *(const short8_t*)&Bs[(wc * 128 + j * 16 + lr) * LDP + kh * 32 + lg * 8];
            #pragma unroll
            for (int i = 0; i < 2; i++)
                #pragma unroll
                for (int j = 0; j < 8; j++)
                    acc[i][j] = __builtin_amdgcn_mfma_f32_16x16x32_bf16(a[i], b[j], acc[i][j], 0, 0, 0);
        }
    }
    float ws[8], wd[8];
    #pragma unroll
    for (int j = 0; j < 8; j++) {
        int c = wc * 128 + j * 16 + lr;
        ws[j] = att_l[c]; wd[j] = att_l[256 + c];
    }
    #pragma unroll
    for (int i = 0; i < 2; i++) {
        #pragma unroll
        for (int b2 = 0; b2 < 4; b2++) {
            int row = bm + wr * 32 + i * 16 + lg * 4 + b2;
            #pragma unroll
            for (int j = 0; j < 8; j++) {
                int col = wc * 128 + j * 16 + lr;
                if (row < M) C[(size_t)row * 256 + col] = f2fp8(acc[i][j][b2]);
            }
            float s0=0.f, s1=0.f, d0=0.f, d1=0.f;
            #pragma unroll
            for (int j = 0; j < 4; j++) { float v = acc[i][j][b2];   s0 += v*ws[j];   d0 += v*wd[j]; }
            #pragma unroll
            for (int j = 4; j < 8; j++) { float v = acc[i][j][b2];   s1 += v*ws[j];   d1 += v*wd[j]; }
            #pragma unroll
            for (int off = 1; off < 16; off <<= 1) {
                s0 += __shfl_xor(s0, off); s1 += __shfl_xor(s1, off);
                d0 += __shfl_xor(d0, off); d1 += __shfl_xor(d1, off);
            }
            if (lr == 0 && row < M) {
                out_as[row * 4 + wc * 2]     = s0;
                out_as[row * 4 + wc * 2 + 1] = s1;
                out_ad[row * 4 + wc * 2]     = d0;
                out_ad[row * 4 + wc * 2 + 1] = d1;
            }
        }
    }
}

// ---------------- K=64 MFMA GEMM (round-8 win, kept) ----------------

template<int NC, bool ATT>
__global__ __launch_bounds__(256) void k_gemm_k64_mfma(const float* __restrict__ A,
        const unsigned short* __restrict__ Bt,
        const float* __restrict__ att_s_g, const float* __restrict__ att_d_g,
        unsigned char* __restrict__ C, float* __restrict__ out_as,
        float* __restrict__ out_ad, int M) {
    constexpr int NF  = NC / 16;               // col frags per wave (8 or 2)
    constexpr int LDP = 72;                    // 64 bf16 + 8 pad
    __shared__ __align__(16) unsigned short As[64 * LDP];
    __shared__ __align__(16) unsigned short Bs[NC * LDP];
    __shared__ float att_l[ATT ? 2 * NC : 1];
    int tid = threadIdx.x;
    int bm = blockIdx.x * 64;
    int wave = tid >> 6, lane = tid & 63, lg = lane >> 4, lr = lane & 15;

    if constexpr (ATT) {
        if (tid < 2 * NC)
            att_l[tid] = (tid < NC) ? att_s_g[tid] : att_d_g[tid - NC];
    }
    {   // stage A: 64 rows x 64 k fp32 -> bf16 (16 values/thread)
        int row = tid >> 2, part = tid & 3;
        int gr = bm + row;
        float4 v0, v1, v2, v3;
        if (gr < M) {
            const float4* p = (const float4*)(A + (size_t)gr * 64 + part * 16);
            v0 = p[0]; v1 = p[1]; v2 = p[2]; v3 = p[3];
        } else {
            v0 = make_float4(0.f,0.f,0.f,0.f); v1 = v0; v2 = v0; v3 = v0;
        }
        unsigned short* w = &As[row * LDP + part * 16];
        w[0]=f2bf(v0.x);  w[1]=f2bf(v0.y);  w[2]=f2bf(v0.z);  w[3]=f2bf(v0.w);
        w[4]=f2bf(v1.x);  w[5]=f2bf(v1.y);  w[6]=f2bf(v1.z);  w[7]=f2bf(v1.w);
        w[8]=f2bf(v2.x);  w[9]=f2bf(v2.y);  w[10]=f2bf(v2.z); w[11]=f2bf(v2.w);
        w[12]=f2bf(v3.x); w[13]=f2bf(v3.y); w[14]=f2bf(v3.z); w[15]=f2bf(v3.w);
    }
    for (int i = tid; i < NC * 8; i += 256) {
        int c = i >> 3, part = i & 7;
        *(uint4*)&Bs[c * LDP + part * 8] = *(const uint4*)(Bt + (size_t)c * 64 + part * 8);
    }
    __syncthreads();

    f32x4 acc[NF] = {};
    short8_t a0 = *(const short8_t*)&As[(wave * 16 + lr) * LDP + lg * 8];
    short8_t a1 = *(const short8_t*)&As[(wave * 16 + lr) * LDP + 32 + lg * 8];
    #pragma unroll
    for (int j = 0; j < NF; j++) {
        short8_t b0 = *(const short8_t*)&Bs[(j * 16 + lr) * LDP + lg * 8];
        short8_t b1 = *(const short8_t*)&Bs[(j * 16 + lr) * LDP + 32 + lg * 8];
        acc[j] = __builtin_amdgcn_mfma_f32_16x16x32_bf16(a0, b0, acc[j], 0, 0, 0);
        acc[j] = __builtin_amdgcn_mfma_f32_16x16x32_bf16(a1, b1, acc[j], 0, 0, 0);
    }
    float ws[NF], wd[NF];
    if constexpr (ATT) {
        #pragma unroll
        for (int j = 0; j < NF; j++) { ws[j] = att_l[j * 16 + lr]; wd[j] = att_l[NC + j * 16 + lr]; }
    }
    #pragma unroll
    for (int b2 = 0; b2 < 4; b2++) {
        int row = bm + wave * 16 + lg * 4 + b2;
        #pragma unroll
        for (int j = 0; j < NF; j++)
            if (row < M) C[(size_t)row * NC + j * 16 + lr] = f2fp8(acc[j][b2]);
        if constexpr (ATT) {   // heads = 2
            float s0=0.f, s1=0.f, d0=0.f, d1=0.f;
            #pragma unroll
            for (int j = 0; j < 4; j++) { float v = acc[j][b2]; s0 += v*ws[j]; d0 += v*wd[j]; }
            #pragma unroll
            for (int j = 4; j < 8; j++) { float v = acc[j][b2]; s1 += v*ws[j]; d1 += v*wd[j]; }
            #pragma unroll
            for (int off = 1; off < 16; off <<= 1) {
                s0 += __shfl_xor(s0, off); s1 += __shfl_xor(s1, off);
                d0 += __shfl_xor(d0, off); d1 += __shfl_xor(d1, off);
            }
            if (lr == 0 && row < M) {
                out_as[row * 2]     = s0;
                out_as[row * 2 + 1] = s1;
                out_ad[row * 2]     = d0;
                out_ad[row * 2 + 1] = d1;
            }
        }
    }
}

// ---------------- fused GAT aggregate, HEADS=4 ----------------
// One wave per node, 1 edge per phase-2 iteration, 4B/lane, unroll 8
// (round-8 lesson: the limiter is loads in flight; no guards in the hot loop).

__global__ __launch_bounds__(256) void k_gat_fused4(const unsigned char* __restrict__ hpre,
        const float* __restrict__ as_n, const float* __restrict__ ad_n,
        const float* __restrict__ bias,
        const int* __restrict__ offs, const int* __restrict__ csr,
        float* __restrict__ out, int n_nodes) {
    __shared__ int   s_off[4][64];
    __shared__ float s_p[4][64 * 4];
    int wif  = threadIdx.x >> 6;
    int lane = threadIdx.x & 63;
    int n = blockIdx.x * 4 + wif;
    if (n >= n_nodes) return;
    const int beg = offs[n];
    const int deg = offs[n + 1] - beg;

    int h_id = lane >> 4, dq = lane & 15;
    const int lane_off = h_id * 64 + dq * 4;   // byte offset within 256 B row

    float4 t = *(const float4*)(ad_n + (size_t)n * 4);
    float adv[4] = {t.x, t.y, t.z, t.w};

    float sumh = 0.f;
    float acc[4] = {};

    for (int j0 = 0; j0 < deg; j0 += 64) {
        int j = j0 + lane;
        int cnt = min(64, deg - j0);
        if (j < deg) {
            int s = csr[beg + j];
            s_off[wif][lane] = s * 256;
            float4 tv = *(const float4*)(as_n + (size_t)s * 4);
            float ev[4] = {tv.x, tv.y, tv.z, tv.w};
            #pragma unroll
            for (int h = 0; h < 4; h++) {
                float e = ev[h] + adv[h];
                e = fmaxf(e, 0.2f * e);
                s_p[wif][lane * 4 + h] = __expf(e);
            }
        }
        #pragma unroll 8
        for (int q = 0; q < cnt; q++) {
            int off = s_off[wif][q];
            float p = s_p[wif][q * 4 + h_id];
            sumh += p;
            unsigned v = *(const unsigned*)(hpre + off + lane_off);
            f32x2 l = fp8lo(v), h2 = fp8hi(v);
            acc[0] += p * l[0]; acc[1] += p * l[1];
            acc[2] += p * h2[0]; acc[3] += p * h2[1];
        }
    }
    float inv = 1.0f / (sumh + 1e-16f);
    float r[4];
    #pragma unroll
    for (int c = 0; c < 4; c++) r[c] = acc[c] * inv;
    #pragma unroll
    for (int c = 0; c < 4; c++) {
        r[c] += __shfl_xor(r[c], 16);
        r[c] += __shfl_xor(r[c], 32);
        r[c] *= 0.25f;
    }
    if (h_id == 0) {
        float4 b = *(const float4*)(bias + dq * 4);
        float4 o;
        o.x = fmaxf(r[0] + b.x, 0.f); o.y = fmaxf(r[1] + b.y, 0.f);
        o.z = fmaxf(r[2] + b.z, 0.f); o.w = fmaxf(r[3] + b.w, 0.f);
        *(float4*)(out + (size_t)n * 64 + dq * 4) = o;
    }
}

// ---------------- fused GAT aggregate, HEADS=2: 32 lanes per node ----------------

__global__ __launch_bounds__(256) void k_gat_fused2(const unsigned char* __restrict__ hpre,
        const float* __restrict__ as_n, const float* __restrict__ ad_n,
        const float* __restrict__ bias,
        const int* __restrict__ offs, const int* __restrict__ csr,
        float* __restrict__ out, int n_nodes) {
    __shared__ int   s_off[4][2][32];
    __shared__ float s_p[4][2][64];
    int wif  = threadIdx.x >> 6;
    int lane = threadIdx.x & 63;
    int half = lane >> 5;                      // node within wave
    int l    = lane & 31;
    int n = blockIdx.x * 8 + wif * 2 + half;
    bool act = n < n_nodes;
    int beg = 0, deg = 0;
    float adv0 = 0.f, adv1 = 0.f;
    if (act) {
        beg = offs[n];
        deg = offs[n + 1] - beg;
        float2 t = *(const float2*)(ad_n + (size_t)n * 2);
        adv0 = t.x; adv1 = t.y;
    }
    int h_id = l >> 4, dq = l & 15;
    const int lane_off = h_id * 64 + dq * 4;   // byte offset within 128 B row

    float sumh = 0.f;
    float acc[4] = {};

    for (int j0 = 0; j0 < deg; j0 += 32) {
        int j = j0 + l;
        int cnt = min(32, deg - j0);
        if (j < deg) {
            int s = csr[beg + j];
            s_off[wif][half][l] = s * 128;
            float2 t = *(const float2*)(as_n + (size_t)s * 2);
            float e0 = t.x + adv0; e0 = fmaxf(e0, 0.2f * e0);
            float e1 = t.y + adv1; e1 = fmaxf(e1, 0.2f * e1);
            s_p[wif][half][l * 2]     = __expf(e0);
            s_p[wif][half][l * 2 + 1] = __expf(e1);
        }
        #pragma unroll 8
        for (int q = 0; q < cnt; q++) {
            int off = s_off[wif][half][q];
            float p = s_p[wif][half][q * 2 + h_id];
            sumh += p;
            unsigned v = *(const unsigned*)(hpre + off + lane_off);
            f32x2 lo = fp8lo(v), hi = fp8hi(v);
            acc[0] += p * lo[0]; acc[1] += p * lo[1];
            acc[2] += p * hi[0]; acc[3] += p * hi[1];
        }
    }
    float inv = 1.0f / (sumh + 1e-16f);
    float r[4];
    #pragma unroll
    for (int c = 0; c < 4; c++) r[c] = acc[c] * inv;
    #pragma unroll
    for (int c = 0; c < 4; c++) {
        r[c] += __shfl_xor(r[c], 16);
        r[c] *= 0.5f;
    }
    if (act && h_id == 0) {
        float4 b = *(const float4*)(bias + dq * 4);
        float4 o;
        o.x = fmaxf(r[0] + b.x, 0.f); o.y = fmaxf(r[1] + b.y, 0.f);
        o.z = fmaxf(r[2] + b.z, 0.f); o.w = fmaxf(r[3] + b.w, 0.f);
        *(float4*)(out + (size_t)n * 64 + dq * 4) = o;
    }
}

// ---------------- fused GCN aggregate + MLP head + sigmoid ----------------

__global__ __launch_bounds__(256) void k_gcn_mlp(const unsigned char* __restrict__ hpre,
        const float* __restrict__ dinv, const float* __restrict__ bias,
        const int* __restrict__ offs, const int* __restrict__ csr,
        const float* __restrict__ Wh1, const float* __restrict__ bh1,
        const float* __restrict__ Wh2, const float* __restrict__ bh2,
        float* __restrict__ out, int n_nodes) {
    __shared__ float w1[512];
    __shared__ float w2[16];
    __shared__ float b1s[16];
    __shared__ float b2s;
    int tid = threadIdx.x;
    for (int i = tid; i < 512; i += 256) w1[i] = Wh1[i];
    if (tid < 16) { w2[tid] = Wh2[tid]; b1s[tid] = bh1[tid]; }
    if (tid == 0) b2s = bh2[0];
    __syncthreads();

    int gid = blockIdx.x * 256 + tid;
    int n = gid >> 3, q = gid & 7;
    if (n >= n_nodes) return;
    const int beg = offs[n], end = offs[n + 1];
    float4 acc = make_float4(0.f,0.f,0.f,0.f);
    #pragma unroll 8
    for (int j = beg; j < end; j++) {
        int s = csr[j];
        float ds = dinv[s];
        unsigned v = *(const unsigned*)(hpre + (size_t)s * 32 + q * 4);
        f32x2 l = fp8lo(v), h2 = fp8hi(v);
        acc.x += ds * l[0]; acc.y += ds * l[1];
        acc.z += ds * h2[0]; acc.w += ds * h2[1];
    }
    float dn = dinv[n];
    float4 b = *(const float4*)(bias + q * 4);
    float x0 = fmaxf(acc.x * dn + b.x, 0.f);
    float x1 = fmaxf(acc.y * dn + b.y, 0.f);
    float x2 = fmaxf(acc.z * dn + b.z, 0.f);
    float x3 = fmaxf(acc.w * dn + b.w, 0.f);

    float pz[16];
    const float* w1r = w1 + q * 64;            // rows q*4..q*4+3, 16 cols each
    #pragma unroll
    for (int jj = 0; jj < 16; jj++)
        pz[jj] = x0 * w1r[jj] + x1 * w1r[16 + jj] + x2 * w1r[32 + jj] + x3 * w1r[48 + jj];
    #pragma unroll
    for (int off = 1; off < 8; off <<= 1)
        #pragma unroll
        for (int jj = 0; jj < 16; jj++) pz[jj] += __shfl_xor(pz[jj], off);
    float acc2 = b2s;
    #pragma unroll
    for (int jj = 0; jj < 16; jj++)
        acc2 += fmaxf(pz[jj] + b1s[jj], 0.f) * w2[jj];
    if (q == 0) out[n] = 1.0f / (1.0f + expf(-acc2));
}

// ---------------- launch ----------------

extern "C" void kernel_launch(void* const* d_in, const int* in_sizes, int n_in,
                              void* d_out, int out_size, void* d_ws, size_t ws_size,
                              hipStream_t stream) {
    const float* x   = (const float*)d_in[0];
    const int*   ei  = (const int*)d_in[1];
    const float* W1  = (const float*)d_in[2];
    const float* a1s = (const float*)d_in[3];
    const float* a1d = (const float*)d_in[4];
    const float* b1  = (const float*)d_in[5];
    const float* W2  = (const float*)d_in[6];
    const float* a2s = (const float*)d_in[7];
    const float* a2d = (const float*)d_in[8];
    const float* b2  = (const float*)d_in[9];
    const float* Wg  = (const float*)d_in[10];
    const float* bg  = (const float*)d_in[11];
    const float* Wh1 = (const float*)d_in[12];
    const float* bh1 = (const float*)d_in[13];
    const float* Wh2 = (const float*)d_in[14];
    const float* bh2 = (const float*)d_in[15];

    const int N = in_sizes[0] / 256;
    const int E = in_sizes[1] / 2;
    const int* srcs = ei;
    const int* dsts = ei + E;

    // workspace layout
    float* R0   = (float*)d_ws;              // N*256 fp32 region; reused as fp8 hpre
    float* R1   = R0 + (size_t)N * 256;      // N*64  : h1 (fp32)
    float* R2   = R1 + (size_t)N * 64;       // N*64  : h2 (fp32)
    float* As_  = R2 + (size_t)N * 64;       // N*4
    float* Ad_  = As_ + (size_t)N * 4;       // N*4
    float* dinv = Ad_ + (size_t)N * 4;       // N
    int* deg    = (int*)(dinv + N);          // N
    int* offs   = deg + N;                   // N+1
    int* cursor = offs + (N + 1);            // N
    int* csr    = cursor + N;                // E + N
    int* parts  = csr + (E + N);             // <=256
    unsigned short* W1t = (unsigned short*)(parts + 256);   // 256*256 bf16
    unsigned short* W2t = W1t + 65536;                      // 128*64 bf16
    unsigned short* Wgt = W2t + 8192;                       // 32*64 bf16
    unsigned char*  HP  = (unsigned char*)R0;               // fp8 h1pre/h2pre/h3pre

    // ---- CSR build (with self loops; XCD-windowed atomics) + weight prep ----
    int wsize = cdiv(N, 8);
    int fillBlocks = cdiv(E, 1024) * 8;
    hipMemsetAsync(deg, 0, (size_t)N * sizeof(int), stream);
    k_count_prep<<<fillBlocks + 256, 256, 0, stream>>>(dsts, E, deg, wsize, fillBlocks,
                                                       W1, W2, Wg, W1t, W2t, Wgt);
    int nch = cdiv(N, 1024);
    k_scan_partial<<<nch, 256, 0, stream>>>(deg, N, parts);
    k_scan_final<<<nch, 256, 0, stream>>>(deg, N, parts, offs, cursor, csr, dinv);
    k_fill_csr_win<<<fillBlocks, 256, 0, stream>>>(srcs, dsts, E, cursor, csr, wsize);

    // ---- GAT layer 1 (heads=4): MFMA GEMM w/ fused att-dots -> fp8 hpre ----
    k_gemm1_mfma<<<cdiv(N, 128), 512, 0, stream>>>(x, W1t, a1s, a1d, HP, As_, Ad_, N);
    k_gat_fused4<<<cdiv(N, 4), 256, 0, stream>>>(HP, As_, Ad_, b1, offs, csr, R1, N);

    // ---- GAT layer 2 (heads=2): MFMA GEMM w/ fused att-dots -> fp8 hpre ----
    k_gemm_k64_mfma<128, true><<<cdiv(N, 64), 256, 0, stream>>>(R1, W2t, a2s, a2d, HP, As_, Ad_, N);
    k_gat_fused2<<<cdiv(N, 8), 256, 0, stream>>>(HP, As_, Ad_, b2, offs, csr, R2, N);

    // ---- GCN GEMM -> fp8, then fused GCN-aggregate + MLP head ----
    k_gemm_k64_mfma<32, false><<<cdiv(N, 64), 256, 0, stream>>>(R2, Wgt, nullptr, nullptr, HP, nullptr, nullptr, N);
    k_gcn_mlp<<<cdiv(N * 8, 256), 256, 0, stream>>>(HP, dinv, bg, offs, csr,
                                                    Wh1, bh1, Wh2, bh2, (float*)d_out, N);
}

// Round 12
// 380.153 us; speedup vs baseline: 1.0073x; 1.0073x over previous
//
#include <hip/hip_runtime.h>
#include <math.h>

static inline int cdiv(int a, int b){ return (a + b - 1) / b; }

typedef __attribute__((ext_vector_type(8))) short short8_t;   // 8 bf16 (4 VGPRs)
typedef __attribute__((ext_vector_type(4))) float f32x4;      // MFMA acc
typedef __attribute__((ext_vector_type(2))) float f32x2;

static __device__ inline unsigned short f2bf(float f) {       // fp32 -> bf16 RTNE
    union { float f; unsigned u; } v; v.f = f;
    unsigned r = v.u + 0x7fff + ((v.u >> 16) & 1);
    return (unsigned short)(r >> 16);
}

// ---- fp8 e4m3fn (OCP) helpers ----
static __device__ inline unsigned char f2fp8(float f) {       // RTNE, saturating
    union { float f; unsigned u; } v; v.f = f;
    unsigned s = (v.u >> 24) & 0x80u;
    v.u &= 0x7fffffffu;
    v.f = fminf(v.f, 448.f);
    unsigned out;
    if (v.u >= (121u << 23)) {                 // |x| >= 2^-6 : normal
        unsigned u = v.u + 0x7FFFFu + ((v.u >> 20) & 1u);
        out = (((u >> 23) - 120u) << 3) | ((u >> 20) & 7u);
    } else {                                   // denormal: round(x * 2^9)
        out = (unsigned)(v.f * 512.f + 0.5f);
    }
    return (unsigned char)(out | s);
}

static __device__ inline float fp8_1(unsigned b) {            // scalar decode (fallback)
    unsigned s = (b & 0x80u) << 24;
    unsigned em = b & 0x7fu;
    union { unsigned u; float f; } n;
    n.u = (((em >> 3) + 120u) << 23) | ((em & 7u) << 20);
    float mag = (em >= 8u) ? n.f : (float)em * 0.001953125f;
    union { unsigned u; float f; } r; r.f = mag; r.u |= s;
    return r.f;
}

static __device__ __forceinline__ f32x2 fp8lo(unsigned v) {   // bytes 0,1
#if __has_builtin(__builtin_amdgcn_cvt_pk_f32_fp8)
    return __builtin_amdgcn_cvt_pk_f32_fp8((int)v, false);
#else
    f32x2 r; r[0] = fp8_1(v & 0xff); r[1] = fp8_1((v >> 8) & 0xff); return r;
#endif
}
static __device__ __forceinline__ f32x2 fp8hi(unsigned v) {   // bytes 2,3
#if __has_builtin(__builtin_amdgcn_cvt_pk_f32_fp8)
    return __builtin_amdgcn_cvt_pk_f32_fp8((int)v, true);
#else
    f32x2 r; r[0] = fp8_1((v >> 16) & 0xff); r[1] = fp8_1(v >> 24); return r;
#endif
}

// ---------------- graph build (CSR by dst, self-loops folded in) ----------------

// XCD-windowed count (blocks < fillBlocks) + weight transpose/cast (trailing blocks).
__global__ __launch_bounds__(256) void k_count_prep(const int* __restrict__ dst, int E,
        int* __restrict__ deg, int wsize, int fillBlocks,
        const float* __restrict__ W1, const float* __restrict__ W2,
        const float* __restrict__ Wg, unsigned short* __restrict__ W1t,
        unsigned short* __restrict__ W2t, unsigned short* __restrict__ Wgt) {
    if (blockIdx.x >= fillBlocks) {            // weight prep tail: 256 blocks
        int t = (blockIdx.x - fillBlocks) * 256 + threadIdx.x;
        if (t < 65536) { int k = t >> 8, c = t & 255; W1t[c * 256 + k] = f2bf(W1[t]); }
        if (t < 8192)  { int k = t >> 7, c = t & 127; W2t[c * 64 + k]  = f2bf(W2[t]); }
        if (t < 2048)  { int k = t >> 5, c = t & 31;  Wgt[c * 64 + k]  = f2bf(Wg[t]); }
        return;
    }
    int win   = blockIdx.x & 7;
    int chunk = blockIdx.x >> 3;
    int lo = win * wsize, hi = lo + wsize;
    int base = (chunk * 256 + threadIdx.x) * 4;
    if (base + 3 < E) {
        int4 d = *(const int4*)(dst + base);
        if (d.x >= lo && d.x < hi) atomicAdd(&deg[d.x], 1);
        if (d.y >= lo && d.y < hi) atomicAdd(&deg[d.y], 1);
        if (d.z >= lo && d.z < hi) atomicAdd(&deg[d.z], 1);
        if (d.w >= lo && d.w < hi) atomicAdd(&deg[d.w], 1);
    } else {
        for (int k = 0; k < 4; k++) {
            int e = base + k;
            if (e < E) { int d = dst[e]; if (d >= lo && d < hi) atomicAdd(&deg[d], 1); }
        }
    }
}

__global__ void k_scan_partial(const int* __restrict__ deg, int n, int* __restrict__ partial) {
    __shared__ int sd[256];
    int base = blockIdx.x * 1024;
    int sum = 0;
    for (int i = threadIdx.x; i < 1024; i += 256) {
        int idx = base + i;
        if (idx < n) sum += deg[idx] + 1;          // +1: self loop
    }
    sd[threadIdx.x] = sum;
    __syncthreads();
    for (int s = 128; s > 0; s >>= 1) {
        if (threadIdx.x < s) sd[threadIdx.x] += sd[threadIdx.x + s];
        __syncthreads();
    }
    if (threadIdx.x == 0) partial[blockIdx.x] = sd[0];
}

// scan with in-kernel lookback + fused: offs, cursor init, self slot, dinv.
__global__ void k_scan_final(const int* __restrict__ deg, int n,
                             const int* __restrict__ partial, int* __restrict__ offs,
                             int* __restrict__ cursor, int* __restrict__ csr,
                             float* __restrict__ dinv) {
    __shared__ int sd[256];
    int tid = threadIdx.x;
    int pre = 0;
    for (int i = tid; i < (int)blockIdx.x; i += 256) pre += partial[i];
    sd[tid] = pre;
    __syncthreads();
    for (int s = 128; s > 0; s >>= 1) {
        if (tid < s) sd[tid] += sd[tid + s];
        __syncthreads();
    }
    int base_pre = sd[0];
    __syncthreads();
    int base = blockIdx.x * 1024;
    int v[4]; int s0 = 0;
    #pragma unroll
    for (int j = 0; j < 4; j++) {
        int idx = base + tid*4 + j;
        v[j] = (idx < n) ? (deg[idx] + 1) : 0;
        s0 += v[j];
    }
    sd[tid] = s0;
    __syncthreads();
    for (int st = 1; st < 256; st <<= 1) {
        int t = (tid >= st) ? sd[tid - st] : 0;
        __syncthreads();
        sd[tid] += t;
        __syncthreads();
    }
    int ex = (tid > 0 ? sd[tid - 1] : 0) + base_pre;
    #pragma unroll
    for (int j = 0; j < 4; j++) {
        int idx = base + tid*4 + j;
        if (idx < n) {
            offs[idx]   = ex;
            cursor[idx] = ex;
            dinv[idx]   = rsqrtf((float)v[j]);
            csr[ex + v[j] - 1] = idx;          // self slot (fill never touches it)
        }
        ex += v[j];
    }
    if (blockIdx.x == gridDim.x - 1 && tid == 255) offs[n] = ex;   // == E + N
}

// XCD-pinned windowed fill; skips src load when quad has no match.
__global__ __launch_bounds__(256) void k_fill_csr_win(const int* __restrict__ src,
        const int* __restrict__ dst, int E,
        int* __restrict__ cursor, int* __restrict__ csr, int wsize) {
    int win   = blockIdx.x & 7;
    int chunk = blockIdx.x >> 3;
    int lo = win * wsize, hi = lo + wsize;
    int base = (chunk * 256 + threadIdx.x) * 4;
    if (base + 3 < E) {
        int4 d = *(const int4*)(dst + base);
        bool ix = d.x >= lo && d.x < hi, iy = d.y >= lo && d.y < hi;
        bool iz = d.z >= lo && d.z < hi, iw = d.w >= lo && d.w < hi;
        if (ix | iy | iz | iw) {
            int4 s = *(const int4*)(src + base);
            if (ix) { int p = atomicAdd(&cursor[d.x], 1); csr[p] = s.x; }
            if (iy) { int p = atomicAdd(&cursor[d.y], 1); csr[p] = s.y; }
            if (iz) { int p = atomicAdd(&cursor[d.z], 1); csr[p] = s.z; }
            if (iw) { int p = atomicAdd(&cursor[d.w], 1); csr[p] = s.w; }
        }
    } else {
        for (int k = 0; k < 4; k++) {
            int e = base + k;
            if (e < E) {
                int d = dst[e];
                if (d >= lo && d < hi) { int p = atomicAdd(&cursor[d], 1); csr[p] = src[e]; }
            }
        }
    }
}

// ---------------- GEMM1: fp8 hpre + fused att-dots, via bf16 MFMA ----------------
// BM=128, BN=256 (full width), BK=64 (kept from r11: ~-2 µs vs BK=32),
// 512 thr / 8 waves, wave tile 32x128.
__global__ __launch_bounds__(512) void k_gemm1_mfma(const float* __restrict__ A,
        const unsigned short* __restrict__ Bt, const float* __restrict__ att_s_g,
        const float* __restrict__ att_d_g, unsigned char* __restrict__ C,
        float* __restrict__ out_as, float* __restrict__ out_ad, int M) {
    constexpr int LDP = 72;                    // 64 bf16 + 8 pad = 144 B row (2-way banks: free)
    __shared__ __align__(16) unsigned short As[128 * LDP];   // 18.4 KB
    __shared__ __align__(16) unsigned short Bs[256 * LDP];   // 36.9 KB
    __shared__ float att_l[512];               // [0:256) att_s, [256:512) att_d (flat col)
    int tid = threadIdx.x;
    int bm = blockIdx.x * 128;
    int wave = tid >> 6, lane = tid & 63;
    int wr = wave >> 1, wc = wave & 1;
    int lg = lane >> 4, lr = lane & 15;

    att_l[tid] = (tid < 256) ? att_s_g[tid] : att_d_g[tid - 256];

    f32x4 acc[2][8] = {};

    for (int k0 = 0; k0 < 256; k0 += 64) {
        __syncthreads();
        {   // stage A: 128 rows x 64 k fp32 -> bf16 (16 floats/thread)
            int row = tid >> 2, part = tid & 3;
            int gr = bm + row;
            float4 v0, v1, v2, v3;
            if (gr < M) {
                const float4* p = (const float4*)(A + (size_t)gr * 256 + k0 + part * 16);
                v0 = p[0]; v1 = p[1]; v2 = p[2]; v3 = p[3];
            } else {
                v0 = make_float4(0.f,0.f,0.f,0.f); v1 = v0; v2 = v0; v3 = v0;
            }
            unsigned short* w = &As[row * LDP + part * 16];
            w[0]=f2bf(v0.x);  w[1]=f2bf(v0.y);  w[2]=f2bf(v0.z);  w[3]=f2bf(v0.w);
            w[4]=f2bf(v1.x);  w[5]=f2bf(v1.y);  w[6]=f2bf(v1.z);  w[7]=f2bf(v1.w);
            w[8]=f2bf(v2.x);  w[9]=f2bf(v2.y);  w[10]=f2bf(v2.z); w[11]=f2bf(v2.w);
            w[12]=f2bf(v3.x); w[13]=f2bf(v3.y); w[14]=f2bf(v3.z); w[15]=f2bf(v3.w);
        }
        {   // stage B: 256 cols x 64 k bf16 copy (64 B/thread)
            int col = tid >> 1, part = tid & 1;
            const uint4* p = (const uint4*)(Bt + (size_t)col * 256 + k0 + part * 32);
            uint4 u0 = p[0], u1 = p[1], u2 = p[2], u3 = p[3];
            unsigned short* w = &Bs[col * LDP + part * 32];
            *(uint4*)(w)      = u0;
            *(uint4*)(w + 8)  = u1;
            *(uint4*)(w + 16) = u2;
            *(uint4*)(w + 24) = u3;
        }
        __syncthreads();
        #pragma unroll
        for (int kh = 0; kh < 2; kh++) {
            short8_t a[2], b[8];
            #pragma unroll
            for (int i = 0; i < 2; i++)
                a[i] = *(const short8_t*)&As[(wr * 32 + i * 16 + lr) * LDP + kh * 32 + lg * 8];
            #pragma unroll
            for (int j = 0; j < 8; j++)
                b[j] = *(const short8_t*)&Bs[(wc * 128 + j * 16 + lr) * LDP + kh * 32 + lg * 8];
            #pragma unroll
            for (int i = 0; i < 2; i++)
                #pragma unroll
                for (int j = 0; j < 8; j++)
                    acc[i][j] = __builtin_amdgcn_mfma_f32_16x16x32_bf16(a[i], b[j], acc[i][j], 0, 0, 0);
        }
    }
    float ws[8], wd[8];
    #pragma unroll
    for (int j = 0; j < 8; j++) {
        int c = wc * 128 + j * 16 + lr;
        ws[j] = att_l[c]; wd[j] = att_l[256 + c];
    }
    #pragma unroll
    for (int i = 0; i < 2; i++) {
        #pragma unroll
        for (int b2 = 0; b2 < 4; b2++) {
            int row = bm + wr * 32 + i * 16 + lg * 4 + b2;
            #pragma unroll
            for (int j = 0; j < 8; j++) {
                int col = wc * 128 + j * 16 + lr;
                if (row < M) C[(size_t)row * 256 + col] = f2fp8(acc[i][j][b2]);
            }
            float s0=0.f, s1=0.f, d0=0.f, d1=0.f;
            #pragma unroll
            for (int j = 0; j < 4; j++) { float v = acc[i][j][b2];   s0 += v*ws[j];   d0 += v*wd[j]; }
            #pragma unroll
            for (int j = 4; j < 8; j++) { float v = acc[i][j][b2];   s1 += v*ws[j];   d1 += v*wd[j]; }
            #pragma unroll
            for (int off = 1; off < 16; off <<= 1) {
                s0 += __shfl_xor(s0, off); s1 += __shfl_xor(s1, off);
                d0 += __shfl_xor(d0, off); d1 += __shfl_xor(d1, off);
            }
            if (lr == 0 && row < M) {
                out_as[row * 4 + wc * 2]     = s0;
                out_as[row * 4 + wc * 2 + 1] = s1;
                out_ad[row * 4 + wc * 2]     = d0;
                out_ad[row * 4 + wc * 2 + 1] = d1;
            }
        }
    }
}

// ---------------- K=64 MFMA GEMM (round-8 win, kept) ----------------

template<int NC, bool ATT>
__global__ __launch_bounds__(256) void k_gemm_k64_mfma(const float* __restrict__ A,
        const unsigned short* __restrict__ Bt,
        const float* __restrict__ att_s_g, const float* __restrict__ att_d_g,
        unsigned char* __restrict__ C, float* __restrict__ out_as,
        float* __restrict__ out_ad, int M) {
    constexpr int NF  = NC / 16;               // col frags per wave (8 or 2)
    constexpr int LDP = 72;                    // 64 bf16 + 8 pad
    __shared__ __align__(16) unsigned short As[64 * LDP];
    __shared__ __align__(16) unsigned short Bs[NC * LDP];
    __shared__ float att_l[ATT ? 2 * NC : 1];
    int tid = threadIdx.x;
    int bm = blockIdx.x * 64;
    int wave = tid >> 6, lane = tid & 63, lg = lane >> 4, lr = lane & 15;

    if constexpr (ATT) {
        if (tid < 2 * NC)
            att_l[tid] = (tid < NC) ? att_s_g[tid] : att_d_g[tid - NC];
    }
    {   // stage A: 64 rows x 64 k fp32 -> bf16 (16 values/thread)
        int row = tid >> 2, part = tid & 3;
        int gr = bm + row;
        float4 v0, v1, v2, v3;
        if (gr < M) {
            const float4* p = (const float4*)(A + (size_t)gr * 64 + part * 16);
            v0 = p[0]; v1 = p[1]; v2 = p[2]; v3 = p[3];
        } else {
            v0 = make_float4(0.f,0.f,0.f,0.f); v1 = v0; v2 = v0; v3 = v0;
        }
        unsigned short* w = &As[row * LDP + part * 16];
        w[0]=f2bf(v0.x);  w[1]=f2bf(v0.y);  w[2]=f2bf(v0.z);  w[3]=f2bf(v0.w);
        w[4]=f2bf(v1.x);  w[5]=f2bf(v1.y);  w[6]=f2bf(v1.z);  w[7]=f2bf(v1.w);
        w[8]=f2bf(v2.x);  w[9]=f2bf(v2.y);  w[10]=f2bf(v2.z); w[11]=f2bf(v2.w);
        w[12]=f2bf(v3.x); w[13]=f2bf(v3.y); w[14]=f2bf(v3.z); w[15]=f2bf(v3.w);
    }
    for (int i = tid; i < NC * 8; i += 256) {
        int c = i >> 3, part = i & 7;
        *(uint4*)&Bs[c * LDP + part * 8] = *(const uint4*)(Bt + (size_t)c * 64 + part * 8);
    }
    __syncthreads();

    f32x4 acc[NF] = {};
    short8_t a0 = *(const short8_t*)&As[(wave * 16 + lr) * LDP + lg * 8];
    short8_t a1 = *(const short8_t*)&As[(wave * 16 + lr) * LDP + 32 + lg * 8];
    #pragma unroll
    for (int j = 0; j < NF; j++) {
        short8_t b0 = *(const short8_t*)&Bs[(j * 16 + lr) * LDP + lg * 8];
        short8_t b1 = *(const short8_t*)&Bs[(j * 16 + lr) * LDP + 32 + lg * 8];
        acc[j] = __builtin_amdgcn_mfma_f32_16x16x32_bf16(a0, b0, acc[j], 0, 0, 0);
        acc[j] = __builtin_amdgcn_mfma_f32_16x16x32_bf16(a1, b1, acc[j], 0, 0, 0);
    }
    float ws[NF], wd[NF];
    if constexpr (ATT) {
        #pragma unroll
        for (int j = 0; j < NF; j++) { ws[j] = att_l[j * 16 + lr]; wd[j] = att_l[NC + j * 16 + lr]; }
    }
    #pragma unroll
    for (int b2 = 0; b2 < 4; b2++) {
        int row = bm + wave * 16 + lg * 4 + b2;
        #pragma unroll
        for (int j = 0; j < NF; j++)
            if (row < M) C[(size_t)row * NC + j * 16 + lr] = f2fp8(acc[j][b2]);
        if constexpr (ATT) {   // heads = 2
            float s0=0.f, s1=0.f, d0=0.f, d1=0.f;
            #pragma unroll
            for (int j = 0; j < 4; j++) { float v = acc[j][b2]; s0 += v*ws[j]; d0 += v*wd[j]; }
            #pragma unroll
            for (int j = 4; j < 8; j++) { float v = acc[j][b2]; s1 += v*ws[j]; d1 += v*wd[j]; }
            #pragma unroll
            for (int off = 1; off < 16; off <<= 1) {
                s0 += __shfl_xor(s0, off); s1 += __shfl_xor(s1, off);
                d0 += __shfl_xor(d0, off); d1 += __shfl_xor(d1, off);
            }
            if (lr == 0 && row < M) {
                out_as[row * 2]     = s0;
                out_as[row * 2 + 1] = s1;
                out_ad[row * 2]     = d0;
                out_ad[row * 2 + 1] = d1;
            }
        }
    }
}

// ---------------- fused GAT aggregate, HEADS=4 ----------------
// One wave per node, 1 edge/iter, 4B/lane, unroll 4 — the measured optimum:
// unroll 8 raised VGPR 28->36, dropped occupancy 73->63%, +4.4 µs (round 11);
// 2-edge/iter guard variant went latency-bound, +17 µs (round 8). Do not touch.

__global__ __launch_bounds__(256) void k_gat_fused4(const unsigned char* __restrict__ hpre,
        const float* __restrict__ as_n, const float* __restrict__ ad_n,
        const float* __restrict__ bias,
        const int* __restrict__ offs, const int* __restrict__ csr,
        float* __restrict__ out, int n_nodes) {
    __shared__ int   s_off[4][64];
    __shared__ float s_p[4][64 * 4];
    int wif  = threadIdx.x >> 6;
    int lane = threadIdx.x & 63;
    int n = blockIdx.x * 4 + wif;
    if (n >= n_nodes) return;
    const int beg = offs[n];
    const int deg = offs[n + 1] - beg;

    int h_id = lane >> 4, dq = lane & 15;
    const int lane_off = h_id * 64 + dq * 4;   // byte offset within 256 B row

    float4 t = *(const float4*)(ad_n + (size_t)n * 4);
    float adv[4] = {t.x, t.y, t.z, t.w};

    float sumh = 0.f;
    float acc[4] = {};

    for (int j0 = 0; j0 < deg; j0 += 64) {
        int j = j0 + lane;
        int cnt = min(64, deg - j0);
        if (j < deg) {
            int s = csr[beg + j];
            s_off[wif][lane] = s * 256;
            float4 tv = *(const float4*)(as_n + (size_t)s * 4);
            float ev[4] = {tv.x, tv.y, tv.z, tv.w};
            #pragma unroll
            for (int h = 0; h < 4; h++) {
                float e = ev[h] + adv[h];
                e = fmaxf(e, 0.2f * e);
                s_p[wif][lane * 4 + h] = __expf(e);
            }
        }
        #pragma unroll 4
        for (int q = 0; q < cnt; q++) {
            int off = s_off[wif][q];
            float p = s_p[wif][q * 4 + h_id];
            sumh += p;
            unsigned v = *(const unsigned*)(hpre + off + lane_off);
            f32x2 l = fp8lo(v), h2 = fp8hi(v);
            acc[0] += p * l[0]; acc[1] += p * l[1];
            acc[2] += p * h2[0]; acc[3] += p * h2[1];
        }
    }
    float inv = 1.0f / (sumh + 1e-16f);
    float r[4];
    #pragma unroll
    for (int c = 0; c < 4; c++) r[c] = acc[c] * inv;
    #pragma unroll
    for (int c = 0; c < 4; c++) {
        r[c] += __shfl_xor(r[c], 16);
        r[c] += __shfl_xor(r[c], 32);
        r[c] *= 0.25f;
    }
    if (h_id == 0) {
        float4 b = *(const float4*)(bias + dq * 4);
        float4 o;
        o.x = fmaxf(r[0] + b.x, 0.f); o.y = fmaxf(r[1] + b.y, 0.f);
        o.z = fmaxf(r[2] + b.z, 0.f); o.w = fmaxf(r[3] + b.w, 0.f);
        *(float4*)(out + (size_t)n * 64 + dq * 4) = o;
    }
}

// ---------------- fused GAT aggregate, HEADS=2: 32 lanes per node ----------------

__global__ __launch_bounds__(256) void k_gat_fused2(const unsigned char* __restrict__ hpre,
        const float* __restrict__ as_n, const float* __restrict__ ad_n,
        const float* __restrict__ bias,
        const int* __restrict__ offs, const int* __restrict__ csr,
        float* __restrict__ out, int n_nodes) {
    __shared__ int   s_off[4][2][32];
    __shared__ float s_p[4][2][64];
    int wif  = threadIdx.x >> 6;
    int lane = threadIdx.x & 63;
    int half = lane >> 5;                      // node within wave
    int l    = lane & 31;
    int n = blockIdx.x * 8 + wif * 2 + half;
    bool act = n < n_nodes;
    int beg = 0, deg = 0;
    float adv0 = 0.f, adv1 = 0.f;
    if (act) {
        beg = offs[n];
        deg = offs[n + 1] - beg;
        float2 t = *(const float2*)(ad_n + (size_t)n * 2);
        adv0 = t.x; adv1 = t.y;
    }
    int h_id = l >> 4, dq = l & 15;
    const int lane_off = h_id * 64 + dq * 4;   // byte offset within 128 B row

    float sumh = 0.f;
    float acc[4] = {};

    for (int j0 = 0; j0 < deg; j0 += 32) {
        int j = j0 + l;
        int cnt = min(32, deg - j0);
        if (j < deg) {
            int s = csr[beg + j];
            s_off[wif][half][l] = s * 128;
            float2 t = *(const float2*)(as_n + (size_t)s * 2);
            float e0 = t.x + adv0; e0 = fmaxf(e0, 0.2f * e0);
            float e1 = t.y + adv1; e1 = fmaxf(e1, 0.2f * e1);
            s_p[wif][half][l * 2]     = __expf(e0);
            s_p[wif][half][l * 2 + 1] = __expf(e1);
        }
        #pragma unroll 4
        for (int q = 0; q < cnt; q++) {
            int off = s_off[wif][half][q];
            float p = s_p[wif][half][q * 2 + h_id];
            sumh += p;
            unsigned v = *(const unsigned*)(hpre + off + lane_off);
            f32x2 lo = fp8lo(v), hi = fp8hi(v);
            acc[0] += p * lo[0]; acc[1] += p * lo[1];
            acc[2] += p * hi[0]; acc[3] += p * hi[1];
        }
    }
    float inv = 1.0f / (sumh + 1e-16f);
    float r[4];
    #pragma unroll
    for (int c = 0; c < 4; c++) r[c] = acc[c] * inv;
    #pragma unroll
    for (int c = 0; c < 4; c++) {
        r[c] += __shfl_xor(r[c], 16);
        r[c] *= 0.5f;
    }
    if (act && h_id == 0) {
        float4 b = *(const float4*)(bias + dq * 4);
        float4 o;
        o.x = fmaxf(r[0] + b.x, 0.f); o.y = fmaxf(r[1] + b.y, 0.f);
        o.z = fmaxf(r[2] + b.z, 0.f); o.w = fmaxf(r[3] + b.w, 0.f);
        *(float4*)(out + (size_t)n * 64 + dq * 4) = o;
    }
}

// ---------------- fused GCN aggregate + MLP head + sigmoid ----------------

__global__ __launch_bounds__(256) void k_gcn_mlp(const unsigned char* __restrict__ hpre,
        const float* __restrict__ dinv, const float* __restrict__ bias,
        const int* __restrict__ offs, const int* __restrict__ csr,
        const float* __restrict__ Wh1, const float* __restrict__ bh1,
        const float* __restrict__ Wh2, const float* __restrict__ bh2,
        float* __restrict__ out, int n_nodes) {
    __shared__ float w1[512];
    __shared__ float w2[16];
    __shared__ float b1s[16];
    __shared__ float b2s;
    int tid = threadIdx.x;
    for (int i = tid; i < 512; i += 256) w1[i] = Wh1[i];
    if (tid < 16) { w2[tid] = Wh2[tid]; b1s[tid] = bh1[tid]; }
    if (tid == 0) b2s = bh2[0];
    __syncthreads();

    int gid = blockIdx.x * 256 + tid;
    int n = gid >> 3, q = gid & 7;
    if (n >= n_nodes) return;
    const int beg = offs[n], end = offs[n + 1];
    float4 acc = make_float4(0.f,0.f,0.f,0.f);
    #pragma unroll 4
    for (int j = beg; j < end; j++) {
        int s = csr[j];
        float ds = dinv[s];
        unsigned v = *(const unsigned*)(hpre + (size_t)s * 32 + q * 4);
        f32x2 l = fp8lo(v), h2 = fp8hi(v);
        acc.x += ds * l[0]; acc.y += ds * l[1];
        acc.z += ds * h2[0]; acc.w += ds * h2[1];
    }
    float dn = dinv[n];
    float4 b = *(const float4*)(bias + q * 4);
    float x0 = fmaxf(acc.x * dn + b.x, 0.f);
    float x1 = fmaxf(acc.y * dn + b.y, 0.f);
    float x2 = fmaxf(acc.z * dn + b.z, 0.f);
    float x3 = fmaxf(acc.w * dn + b.w, 0.f);

    float pz[16];
    const float* w1r = w1 + q * 64;            // rows q*4..q*4+3, 16 cols each
    #pragma unroll
    for (int jj = 0; jj < 16; jj++)
        pz[jj] = x0 * w1r[jj] + x1 * w1r[16 + jj] + x2 * w1r[32 + jj] + x3 * w1r[48 + jj];
    #pragma unroll
    for (int off = 1; off < 8; off <<= 1)
        #pragma unroll
        for (int jj = 0; jj < 16; jj++) pz[jj] += __shfl_xor(pz[jj], off);
    float acc2 = b2s;
    #pragma unroll
    for (int jj = 0; jj < 16; jj++)
        acc2 += fmaxf(pz[jj] + b1s[jj], 0.f) * w2[jj];
    if (q == 0) out[n] = 1.0f / (1.0f + expf(-acc2));
}

// ---------------- launch ----------------

extern "C" void kernel_launch(void* const* d_in, const int* in_sizes, int n_in,
                              void* d_out, int out_size, void* d_ws, size_t ws_size,
                              hipStream_t stream) {
    const float* x   = (const float*)d_in[0];
    const int*   ei  = (const int*)d_in[1];
    const float* W1  = (const float*)d_in[2];
    const float* a1s = (const float*)d_in[3];
    const float* a1d = (const float*)d_in[4];
    const float* b1  = (const float*)d_in[5];
    const float* W2  = (const float*)d_in[6];
    const float* a2s = (const float*)d_in[7];
    const float* a2d = (const float*)d_in[8];
    const float* b2  = (const float*)d_in[9];
    const float* Wg  = (const float*)d_in[10];
    const float* bg  = (const float*)d_in[11];
    const float* Wh1 = (const float*)d_in[12];
    const float* bh1 = (const float*)d_in[13];
    const float* Wh2 = (const float*)d_in[14];
    const float* bh2 = (const float*)d_in[15];

    const int N = in_sizes[0] / 256;
    const int E = in_sizes[1] / 2;
    const int* srcs = ei;
    const int* dsts = ei + E;

    // workspace layout
    float* R0   = (float*)d_ws;              // N*256 fp32 region; reused as fp8 hpre
    float* R1   = R0 + (size_t)N * 256;      // N*64  : h1 (fp32)
    float* R2   = R1 + (size_t)N * 64;       // N*64  : h2 (fp32)
    float* As_  = R2 + (size_t)N * 64;       // N*4
    float* Ad_  = As_ + (size_t)N * 4;       // N*4
    float* dinv = Ad_ + (size_t)N * 4;       // N
    int* deg    = (int*)(dinv + N);          // N
    int* offs   = deg + N;                   // N+1
    int* cursor = offs + (N + 1);            // N
    int* csr    = cursor + N;                // E + N
    int* parts  = csr + (E + N);             // <=256
    unsigned short* W1t = (unsigned short*)(parts + 256);   // 256*256 bf16
    unsigned short* W2t = W1t + 65536;                      // 128*64 bf16
    unsigned short* Wgt = W2t + 8192;                       // 32*64 bf16
    unsigned char*  HP  = (unsigned char*)R0;               // fp8 h1pre/h2pre/h3pre

    // ---- CSR build (with self loops; XCD-windowed atomics) + weight prep ----
    int wsize = cdiv(N, 8);
    int fillBlocks = cdiv(E, 1024) * 8;
    hipMemsetAsync(deg, 0, (size_t)N * sizeof(int), stream);
    k_count_prep<<<fillBlocks + 256, 256, 0, stream>>>(dsts, E, deg, wsize, fillBlocks,
                                                       W1, W2, Wg, W1t, W2t, Wgt);
    int nch = cdiv(N, 1024);
    k_scan_partial<<<nch, 256, 0, stream>>>(deg, N, parts);
    k_scan_final<<<nch, 256, 0, stream>>>(deg, N, parts, offs, cursor, csr, dinv);
    k_fill_csr_win<<<fillBlocks, 256, 0, stream>>>(srcs, dsts, E, cursor, csr, wsize);

    // ---- GAT layer 1 (heads=4): MFMA GEMM w/ fused att-dots -> fp8 hpre ----
    k_gemm1_mfma<<<cdiv(N, 128), 512, 0, stream>>>(x, W1t, a1s, a1d, HP, As_, Ad_, N);
    k_gat_fused4<<<cdiv(N, 4), 256, 0, stream>>>(HP, As_, Ad_, b1, offs, csr, R1, N);

    // ---- GAT layer 2 (heads=2): MFMA GEMM w/ fused att-dots -> fp8 hpre ----
    k_gemm_k64_mfma<128, true><<<cdiv(N, 64), 256, 0, stream>>>(R1, W2t, a2s, a2d, HP, As_, Ad_, N);
    k_gat_fused2<<<cdiv(N, 8), 256, 0, stream>>>(HP, As_, Ad_, b2, offs, csr, R2, N);

    // ---- GCN GEMM -> fp8, then fused GCN-aggregate + MLP head ----
    k_gemm_k64_mfma<32, false><<<cdiv(N, 64), 256, 0, stream>>>(R2, Wgt, nullptr, nullptr, HP, nullptr, nullptr, N);
    k_gcn_mlp<<<cdiv(N * 8, 256), 256, 0, stream>>>(HP, dinv, bg, offs, csr,
                                                    Wh1, bh1, Wh2, bh2, (float*)d_out, N);
}